// Round 1
// baseline (867.499 us; speedup 1.0000x reference)
//
#include <hip/hip_runtime.h>

#define D 128

// ---------------------------------------------------------------------------
// CSR build: histogram -> scan -> fill
// ---------------------------------------------------------------------------

__global__ __launch_bounds__(256) void k_hist(const int* __restrict__ dst,
                                              int* __restrict__ degi, int e) {
    int i = blockIdx.x * 256 + threadIdx.x;
    if (i < e) atomicAdd(&degi[dst[i]], 1);
}

// Per-block exclusive scan of 1024 elements (256 thr x 4), also computes
// dis[v] = rsqrt(deg_real + 1)  (the +1 is the self-loop).
__global__ __launch_bounds__(256) void k_scan_local(const int* __restrict__ degi,
                                                    int* __restrict__ rowptr,
                                                    int* __restrict__ blocksums,
                                                    float* __restrict__ dis, int n) {
    __shared__ int sd[256];
    int tid  = threadIdx.x;
    int base = blockIdx.x * 1024 + tid * 4;
    int v0 = 0, v1 = 0, v2 = 0, v3 = 0;
    if (base + 0 < n) v0 = degi[base + 0];
    if (base + 1 < n) v1 = degi[base + 1];
    if (base + 2 < n) v2 = degi[base + 2];
    if (base + 3 < n) v3 = degi[base + 3];
    if (base + 0 < n) dis[base + 0] = rsqrtf((float)(v0 + 1));
    if (base + 1 < n) dis[base + 1] = rsqrtf((float)(v1 + 1));
    if (base + 2 < n) dis[base + 2] = rsqrtf((float)(v2 + 1));
    if (base + 3 < n) dis[base + 3] = rsqrtf((float)(v3 + 1));
    int tsum = v0 + v1 + v2 + v3;
    sd[tid] = tsum;
    __syncthreads();
    for (int off = 1; off < 256; off <<= 1) {
        int add = (tid >= off) ? sd[tid - off] : 0;
        __syncthreads();
        sd[tid] += add;
        __syncthreads();
    }
    int incl = sd[tid];
    int excl = incl - tsum;
    if (tid == 255) blocksums[blockIdx.x] = incl;
    if (base + 0 < n) rowptr[base + 0] = excl;
    if (base + 1 < n) rowptr[base + 1] = excl + v0;
    if (base + 2 < n) rowptr[base + 2] = excl + v0 + v1;
    if (base + 3 < n) rowptr[base + 3] = excl + v0 + v1 + v2;
}

// Exclusive scan of up to 128 block sums (single block).
__global__ __launch_bounds__(128) void k_scan_bsum(int* __restrict__ bs, int nb) {
    __shared__ int sd[128];
    int t = threadIdx.x;
    int v = (t < nb) ? bs[t] : 0;
    sd[t] = v;
    __syncthreads();
    for (int off = 1; off < 128; off <<= 1) {
        int add = (t >= off) ? sd[t - off] : 0;
        __syncthreads();
        sd[t] += add;
        __syncthreads();
    }
    if (t < nb) bs[t] = sd[t] - v;  // exclusive
}

__global__ __launch_bounds__(256) void k_scan_add(int* __restrict__ rowptr,
                                                  int* __restrict__ cursor,
                                                  const int* __restrict__ blocksums,
                                                  int n, int total) {
    int i = blockIdx.x * 256 + threadIdx.x;
    if (i < n) {
        int r = rowptr[i] + blocksums[i >> 10];
        rowptr[i] = r;
        cursor[i] = r;
    }
    if (i == 0) rowptr[n] = total;
}

__global__ __launch_bounds__(256) void k_fill(const int* __restrict__ src,
                                              const int* __restrict__ dst,
                                              int* __restrict__ cursor,
                                              int* __restrict__ col, int e) {
    int i = blockIdx.x * 256 + threadIdx.x;
    if (i < e) {
        int pos = atomicAdd(&cursor[dst[i]], 1);
        col[pos] = src[i];
    }
}

// ---------------------------------------------------------------------------
// hs = dis[v] * (x @ W[l]) : W (64KB) + 16-row x tile (8KB) in dynamic LDS.
// Block = 256 thr (4 waves); each wave computes 4 rows; lane -> cols (l, l+64).
// ---------------------------------------------------------------------------
__global__ __launch_bounds__(256) void k_gemm(const float* __restrict__ x,
                                              const float* __restrict__ W,
                                              const float* __restrict__ dis,
                                              float* __restrict__ h, int n) {
    extern __shared__ float smem[];
    float*  Ws  = smem;           // 128*128
    float4* xs4 = (float4*)(smem + D * D);  // 16 rows * 128 = 512 float4
    // cooperative load of W (16384 floats = 4096 float4, 16 per thread)
    {
        const float4* W4  = (const float4*)W;
        float4*       Ws4 = (float4*)Ws;
#pragma unroll
        for (int i = 0; i < 16; ++i)
            Ws4[threadIdx.x + i * 256] = W4[threadIdx.x + i * 256];
    }
    int wave = threadIdx.x >> 6;
    int lane = threadIdx.x & 63;
    const float4* X4 = (const float4*)x;
    size_t n4 = (size_t)n * (D / 4);

    for (int gbase = blockIdx.x * 16; gbase < n; gbase += gridDim.x * 16) {
        __syncthreads();  // xs reuse from previous iter (also orders W load, iter 0)
        size_t base4 = (size_t)gbase * (D / 4);
        int i0 = threadIdx.x * 2, i1 = threadIdx.x * 2 + 1;
        if (gbase + 16 <= n) {
            xs4[i0] = X4[base4 + i0];
            xs4[i1] = X4[base4 + i1];
        } else {
            if (base4 + i0 < n4) xs4[i0] = X4[base4 + i0];
            if (base4 + i1 < n4) xs4[i1] = X4[base4 + i1];
        }
        __syncthreads();

        int   r0  = wave * 4;  // local row base within the 16-row tile
        float a0l = 0.f, a0h = 0.f, a1l = 0.f, a1h = 0.f;
        float a2l = 0.f, a2h = 0.f, a3l = 0.f, a3h = 0.f;
#pragma unroll 4
        for (int k4 = 0; k4 < 32; ++k4) {
            float4 x0 = xs4[(r0 + 0) * 32 + k4];
            float4 x1 = xs4[(r0 + 1) * 32 + k4];
            float4 x2 = xs4[(r0 + 2) * 32 + k4];
            float4 x3 = xs4[(r0 + 3) * 32 + k4];
#pragma unroll
            for (int i = 0; i < 4; ++i) {
                float wl = Ws[(4 * k4 + i) * D + lane];
                float wh = Ws[(4 * k4 + i) * D + lane + 64];
                float e0 = (&x0.x)[i], e1 = (&x1.x)[i];
                float e2 = (&x2.x)[i], e3 = (&x3.x)[i];
                a0l = fmaf(e0, wl, a0l); a0h = fmaf(e0, wh, a0h);
                a1l = fmaf(e1, wl, a1l); a1h = fmaf(e1, wh, a1h);
                a2l = fmaf(e2, wl, a2l); a2h = fmaf(e2, wh, a2h);
                a3l = fmaf(e3, wl, a3l); a3h = fmaf(e3, wh, a3h);
            }
        }
        int r = gbase + r0;
        if (r + 3 < n) {
            float d0 = dis[r], d1 = dis[r + 1], d2 = dis[r + 2], d3 = dis[r + 3];
            float* hp = h + (size_t)r * D;
            hp[lane] = a0l * d0;          hp[lane + 64] = a0h * d0;
            hp[D + lane] = a1l * d1;      hp[D + lane + 64] = a1h * d1;
            hp[2 * D + lane] = a2l * d2;  hp[2 * D + lane + 64] = a2h * d2;
            hp[3 * D + lane] = a3l * d3;  hp[3 * D + lane + 64] = a3h * d3;
        } else {
            float acc_l[4] = {a0l, a1l, a2l, a3l};
            float acc_h[4] = {a0h, a1h, a2h, a3h};
            for (int q = 0; q < 4; ++q) {
                if (r + q < n) {
                    float dq = dis[r + q];
                    float* hp = h + (size_t)(r + q) * D;
                    hp[lane] = acc_l[q] * dq;
                    hp[lane + 64] = acc_h[q] * dq;
                }
            }
        }
    }
}

// ---------------------------------------------------------------------------
// out[v] = relu( dis[v] * (hs[v] + sum_{s in N(v)} hs[s]) + b )
// One wave per node; lane holds cols (2l, 2l+1) as float2; 4-way unrolled
// neighbor loop for memory-level parallelism. No atomics.
// ---------------------------------------------------------------------------
__global__ __launch_bounds__(256) void k_agg(const float* __restrict__ h,
                                             const int* __restrict__ rowptr,
                                             const int* __restrict__ col,
                                             const float* __restrict__ dis,
                                             const float* __restrict__ b,
                                             float* __restrict__ out, int n) {
    int wave = threadIdx.x >> 6;
    int lane = threadIdx.x & 63;
    int v = blockIdx.x * 4 + wave;
    if (v >= n) return;
    const float2* h2 = (const float2*)h;
    float2 self = h2[(size_t)v * 64 + lane];
    float ax0 = self.x, ay0 = self.y;
    float ax1 = 0.f, ay1 = 0.f, ax2 = 0.f, ay2 = 0.f, ax3 = 0.f, ay3 = 0.f;
    int beg = rowptr[v], end = rowptr[v + 1];
    int i = beg;
    for (; i + 4 <= end; i += 4) {
        int s0 = col[i], s1 = col[i + 1], s2 = col[i + 2], s3 = col[i + 3];
        float2 m0 = h2[(size_t)s0 * 64 + lane];
        float2 m1 = h2[(size_t)s1 * 64 + lane];
        float2 m2 = h2[(size_t)s2 * 64 + lane];
        float2 m3 = h2[(size_t)s3 * 64 + lane];
        ax0 += m0.x; ay0 += m0.y;
        ax1 += m1.x; ay1 += m1.y;
        ax2 += m2.x; ay2 += m2.y;
        ax3 += m3.x; ay3 += m3.y;
    }
    for (; i < end; ++i) {
        int s = col[i];
        float2 m = h2[(size_t)s * 64 + lane];
        ax0 += m.x; ay0 += m.y;
    }
    float  dv = dis[v];
    float2 bb = ((const float2*)b)[lane];
    float2 r;
    r.x = fmaxf(0.f, (ax0 + ax1 + ax2 + ax3) * dv + bb.x);
    r.y = fmaxf(0.f, (ay0 + ay1 + ay2 + ay3) * dv + bb.y);
    ((float2*)out)[(size_t)v * 64 + lane] = r;
}

// ---------------------------------------------------------------------------

extern "C" void kernel_launch(void* const* d_in, const int* in_sizes, int n_in,
                              void* d_out, int out_size, void* d_ws, size_t ws_size,
                              hipStream_t stream) {
    const float* x0 = (const float*)d_in[0];
    const int*   ei = (const int*)d_in[1];
    const float* W  = (const float*)d_in[2];
    const float* b  = (const float*)d_in[3];

    int n = in_sizes[0] / D;        // 100000
    int e = in_sizes[1] / 2;        // 1600000
    int L = in_sizes[2] / (D * D);  // 3

    const int* srcI = ei;       // edge_index[0] : message source
    const int* dstI = ei + e;   // edge_index[1] : aggregation target

    // workspace carve (H first: keeps 16B alignment for float4)
    float* H         = (float*)d_ws;                  // n*128 floats (51.2 MB)
    int*   degi      = (int*)(H + (size_t)n * D);     // n
    int*   rowptr    = degi + n;                      // n+1
    int*   cursor    = rowptr + n + 1;                // n
    float* dis       = (float*)(cursor + n);          // n
    int*   col       = (int*)(dis + n);               // e
    int*   blocksums = col + e;                       // <=128

    hipMemsetAsync(degi, 0, (size_t)n * sizeof(int), stream);

    int eb = (e + 255) / 256;
    k_hist<<<eb, 256, 0, stream>>>(dstI, degi, e);

    int nscan = (n + 1023) / 1024;  // 98 blocks
    k_scan_local<<<nscan, 256, 0, stream>>>(degi, rowptr, blocksums, dis, n);
    k_scan_bsum<<<1, 128, 0, stream>>>(blocksums, nscan);
    int nb2 = (n + 255) / 256;
    k_scan_add<<<nb2, 256, 0, stream>>>(rowptr, cursor, blocksums, n, e);
    k_fill<<<eb, 256, 0, stream>>>(srcI, dstI, cursor, col, e);

    float*       out = (float*)d_out;
    const float* xin = x0;
    size_t lds_bytes = (size_t)(D * D + 16 * D) * sizeof(float);  // 72 KB
    for (int l = 0; l < L; ++l) {
        k_gemm<<<512, 256, lds_bytes, stream>>>(xin, W + (size_t)l * D * D, dis, H, n);
        k_agg<<<(n + 3) / 4, 256, 0, stream>>>(H, rowptr, col, dis, b + (size_t)l * D, out, n);
        xin = out;
    }
}

// Round 3
// 790.069 us; speedup vs baseline: 1.0980x; 1.0980x over previous
//
#include <hip/hip_runtime.h>

#define D 128
#define NSHARD 8

// ---------------------------------------------------------------------------
// CSR build: XCD-sharded histogram -> scan -> XCD-sharded fill.
// Shard s = blockIdx & 7 handles only dst in [s*per, (s+1)*per): under the
// default blockIdx%8 -> XCD mapping, all writes to one col/degi line come
// from a single XCD, so L2 assembles full lines (perf-only assumption).
// ---------------------------------------------------------------------------

__global__ __launch_bounds__(256) void k_hist(const int* __restrict__ dst,
                                              int* __restrict__ degi, int e, int n) {
    int s   = blockIdx.x & (NSHARD - 1);
    int per = (n + NSHARD - 1) / NSHARD;
    int lo  = s * per;
    int hi  = min(n, lo + per);
    const int4* d4 = (const int4*)dst;
    int e4     = e >> 2;
    int idx    = (blockIdx.x >> 3) * 256 + threadIdx.x;
    int stride = (gridDim.x >> 3) * 256;
    for (int i = idx; i < e4; i += stride) {
        int4 d = d4[i];
        if (d.x >= lo && d.x < hi) atomicAdd(&degi[d.x], 1);
        if (d.y >= lo && d.y < hi) atomicAdd(&degi[d.y], 1);
        if (d.z >= lo && d.z < hi) atomicAdd(&degi[d.z], 1);
        if (d.w >= lo && d.w < hi) atomicAdd(&degi[d.w], 1);
    }
    if (idx == 0) {  // scalar tail (e % 4), once per shard
        for (int i = e4 * 4; i < e; ++i) {
            int d = dst[i];
            if (d >= lo && d < hi) atomicAdd(&degi[d], 1);
        }
    }
}

// Per-block exclusive scan of 1024 elements (256 thr x 4), also computes
// dis[v] = rsqrt(deg_real + 1)  (the +1 is the self-loop).
__global__ __launch_bounds__(256) void k_scan_local(const int* __restrict__ degi,
                                                    int* __restrict__ rowptr,
                                                    int* __restrict__ blocksums,
                                                    float* __restrict__ dis, int n) {
    __shared__ int sd[256];
    int tid  = threadIdx.x;
    int base = blockIdx.x * 1024 + tid * 4;
    int v0 = 0, v1 = 0, v2 = 0, v3 = 0;
    if (base + 0 < n) v0 = degi[base + 0];
    if (base + 1 < n) v1 = degi[base + 1];
    if (base + 2 < n) v2 = degi[base + 2];
    if (base + 3 < n) v3 = degi[base + 3];
    if (base + 0 < n) dis[base + 0] = rsqrtf((float)(v0 + 1));
    if (base + 1 < n) dis[base + 1] = rsqrtf((float)(v1 + 1));
    if (base + 2 < n) dis[base + 2] = rsqrtf((float)(v2 + 1));
    if (base + 3 < n) dis[base + 3] = rsqrtf((float)(v3 + 1));
    int tsum = v0 + v1 + v2 + v3;
    sd[tid] = tsum;
    __syncthreads();
    for (int off = 1; off < 256; off <<= 1) {
        int add = (tid >= off) ? sd[tid - off] : 0;
        __syncthreads();
        sd[tid] += add;
        __syncthreads();
    }
    int incl = sd[tid];
    int excl = incl - tsum;
    if (tid == 255) blocksums[blockIdx.x] = incl;
    if (base + 0 < n) rowptr[base + 0] = excl;
    if (base + 1 < n) rowptr[base + 1] = excl + v0;
    if (base + 2 < n) rowptr[base + 2] = excl + v0 + v1;
    if (base + 3 < n) rowptr[base + 3] = excl + v0 + v1 + v2;
}

__global__ __launch_bounds__(128) void k_scan_bsum(int* __restrict__ bs, int nb) {
    __shared__ int sd[128];
    int t = threadIdx.x;
    int v = (t < nb) ? bs[t] : 0;
    sd[t] = v;
    __syncthreads();
    for (int off = 1; off < 128; off <<= 1) {
        int add = (t >= off) ? sd[t - off] : 0;
        __syncthreads();
        sd[t] += add;
        __syncthreads();
    }
    if (t < nb) bs[t] = sd[t] - v;  // exclusive
}

__global__ __launch_bounds__(256) void k_scan_add(int* __restrict__ rowptr,
                                                  int* __restrict__ cursor,
                                                  const int* __restrict__ blocksums,
                                                  int n, int total) {
    int i = blockIdx.x * 256 + threadIdx.x;
    if (i < n) {
        int r = rowptr[i] + blocksums[i >> 10];
        rowptr[i] = r;
        cursor[i] = r;
    }
    if (i == 0) rowptr[n] = total;
}

__global__ __launch_bounds__(256) void k_fill(const int* __restrict__ src,
                                              const int* __restrict__ dst,
                                              int* __restrict__ cursor,
                                              int* __restrict__ col, int e, int n) {
    int s   = blockIdx.x & (NSHARD - 1);
    int per = (n + NSHARD - 1) / NSHARD;
    int lo  = s * per;
    int hi  = min(n, lo + per);
    const int4* d4 = (const int4*)dst;
    const int4* s4 = (const int4*)src;
    int e4     = e >> 2;
    int idx    = (blockIdx.x >> 3) * 256 + threadIdx.x;
    int stride = (gridDim.x >> 3) * 256;
    for (int i = idx; i < e4; i += stride) {
        int4 d = d4[i];
        bool any = (d.x >= lo && d.x < hi) || (d.y >= lo && d.y < hi) ||
                   (d.z >= lo && d.z < hi) || (d.w >= lo && d.w < hi);
        if (!any) continue;
        int4 sc = s4[i];
        if (d.x >= lo && d.x < hi) col[atomicAdd(&cursor[d.x], 1)] = sc.x;
        if (d.y >= lo && d.y < hi) col[atomicAdd(&cursor[d.y], 1)] = sc.y;
        if (d.z >= lo && d.z < hi) col[atomicAdd(&cursor[d.z], 1)] = sc.z;
        if (d.w >= lo && d.w < hi) col[atomicAdd(&cursor[d.w], 1)] = sc.w;
    }
    if (idx == 0) {  // scalar tail, once per shard
        for (int i = e4 * 4; i < e; ++i) {
            int d = dst[i];
            if (d >= lo && d < hi) col[atomicAdd(&cursor[d], 1)] = src[i];
        }
    }
}

// ---------------------------------------------------------------------------
// hs = dis[v] * (x @ W[l]) : W (64KB) + 32-row x tile (16KB) in dynamic LDS.
// Block = 256 thr (4 waves); wave computes 8 rows; thread cols {2l, 2l+1}.
// Per k4: 8 broadcast ds_read_b128 (x) + 4 ds_read_b64 (W) feed 64 FMAs.
// ---------------------------------------------------------------------------
__global__ __launch_bounds__(256) void k_gemm(const float* __restrict__ x,
                                              const float* __restrict__ W,
                                              const float* __restrict__ dis,
                                              float* __restrict__ h, int n) {
    extern __shared__ float smem[];
    float*  Ws  = smem;                       // 128*128
    float2* Ws2 = (float2*)smem;
    float4* xs4 = (float4*)(smem + D * D);    // 32 rows * 128 = 1024 float4
    {
        const float4* W4  = (const float4*)W;
        float4*       Ws4 = (float4*)Ws;
#pragma unroll
        for (int i = 0; i < 16; ++i)
            Ws4[threadIdx.x + i * 256] = W4[threadIdx.x + i * 256];
    }
    int wave = threadIdx.x >> 6;
    int lane = threadIdx.x & 63;
    const float4* X4 = (const float4*)x;
    size_t n4     = (size_t)n * (D / 4);
    int    ntiles = (n + 31) / 32;

    for (int tile = blockIdx.x; tile < ntiles; tile += gridDim.x) {
        int gbase = tile * 32;
        __syncthreads();  // xs reuse from previous iter (also orders W load, iter 0)
        size_t base4 = (size_t)gbase * (D / 4);
        if (gbase + 32 <= n) {
#pragma unroll
            for (int j = 0; j < 4; ++j)
                xs4[threadIdx.x + j * 256] = X4[base4 + threadIdx.x + j * 256];
        } else {
#pragma unroll
            for (int j = 0; j < 4; ++j) {
                size_t gi = base4 + threadIdx.x + j * 256;
                if (gi < n4) xs4[threadIdx.x + j * 256] = X4[gi];
            }
        }
        __syncthreads();

        int    r0 = wave * 8;
        float2 acc[8];
#pragma unroll
        for (int r = 0; r < 8; ++r) { acc[r].x = 0.f; acc[r].y = 0.f; }

#pragma unroll 4
        for (int k4 = 0; k4 < 32; ++k4) {
            float4 xr[8];
#pragma unroll
            for (int r = 0; r < 8; ++r) xr[r] = xs4[(r0 + r) * 32 + k4];
#pragma unroll
            for (int i = 0; i < 4; ++i) {
                float2 w = Ws2[(4 * k4 + i) * 64 + lane];
#pragma unroll
                for (int r = 0; r < 8; ++r) {
                    float e = (&xr[r].x)[i];
                    acc[r].x = fmaf(e, w.x, acc[r].x);
                    acc[r].y = fmaf(e, w.y, acc[r].y);
                }
            }
        }
        float2* h2 = (float2*)h;
        if (gbase + 32 <= n) {
#pragma unroll
            for (int r = 0; r < 8; ++r) {
                int   row = gbase + r0 + r;
                float dv  = dis[row];
                float2 o; o.x = acc[r].x * dv; o.y = acc[r].y * dv;
                h2[(size_t)row * 64 + lane] = o;
            }
        } else {
#pragma unroll
            for (int r = 0; r < 8; ++r) {
                int row = gbase + r0 + r;
                if (row < n) {
                    float dv = dis[row];
                    float2 o; o.x = acc[r].x * dv; o.y = acc[r].y * dv;
                    h2[(size_t)row * 64 + lane] = o;
                }
            }
        }
    }
}

// ---------------------------------------------------------------------------
// out[v] = relu( dis[v] * (hs[v] + sum_{s in N(v)} hs[s]) + b )
// Half-wave (32 lanes x float4 = 512B) per node; 2 nodes/wave, 8 nodes/block.
// 4-way unrolled neighbor loop: 4KB in flight per wave per step. No atomics.
// ---------------------------------------------------------------------------
__global__ __launch_bounds__(256) void k_agg(const float* __restrict__ h,
                                             const int* __restrict__ rowptr,
                                             const int* __restrict__ col,
                                             const float* __restrict__ dis,
                                             const float* __restrict__ b,
                                             float* __restrict__ out, int n) {
    int wave = threadIdx.x >> 6;
    int lane = threadIdx.x & 63;
    int half = lane >> 5;
    int hl   = lane & 31;
    int v = blockIdx.x * 8 + wave * 2 + half;
    if (v >= n) return;
    const float4* h4 = (const float4*)h;
    float4 s0 = h4[(size_t)v * 32 + hl];
    float ax0 = s0.x, ay0 = s0.y, az0 = s0.z, aw0 = s0.w;
    float ax1 = 0.f, ay1 = 0.f, az1 = 0.f, aw1 = 0.f;
    float ax2 = 0.f, ay2 = 0.f, az2 = 0.f, aw2 = 0.f;
    float ax3 = 0.f, ay3 = 0.f, az3 = 0.f, aw3 = 0.f;
    int beg = rowptr[v], end = rowptr[v + 1];
    int i = beg;
    for (; i + 4 <= end; i += 4) {
        int c0 = col[i], c1 = col[i + 1], c2 = col[i + 2], c3 = col[i + 3];
        float4 m0 = h4[(size_t)c0 * 32 + hl];
        float4 m1 = h4[(size_t)c1 * 32 + hl];
        float4 m2 = h4[(size_t)c2 * 32 + hl];
        float4 m3 = h4[(size_t)c3 * 32 + hl];
        ax0 += m0.x; ay0 += m0.y; az0 += m0.z; aw0 += m0.w;
        ax1 += m1.x; ay1 += m1.y; az1 += m1.z; aw1 += m1.w;
        ax2 += m2.x; ay2 += m2.y; az2 += m2.z; aw2 += m2.w;
        ax3 += m3.x; ay3 += m3.y; az3 += m3.z; aw3 += m3.w;
    }
    for (; i < end; ++i) {
        int c = col[i];
        float4 m = h4[(size_t)c * 32 + hl];
        ax0 += m.x; ay0 += m.y; az0 += m.z; aw0 += m.w;
    }
    float  dv = dis[v];
    float4 bb = ((const float4*)b)[hl];
    float4 r;
    r.x = fmaxf(0.f, (ax0 + ax1 + ax2 + ax3) * dv + bb.x);
    r.y = fmaxf(0.f, (ay0 + ay1 + ay2 + ay3) * dv + bb.y);
    r.z = fmaxf(0.f, (az0 + az1 + az2 + az3) * dv + bb.z);
    r.w = fmaxf(0.f, (aw0 + aw1 + aw2 + aw3) * dv + bb.w);
    ((float4*)out)[(size_t)v * 32 + hl] = r;
}

// ---------------------------------------------------------------------------

extern "C" void kernel_launch(void* const* d_in, const int* in_sizes, int n_in,
                              void* d_out, int out_size, void* d_ws, size_t ws_size,
                              hipStream_t stream) {
    const float* x0 = (const float*)d_in[0];
    const int*   ei = (const int*)d_in[1];
    const float* W  = (const float*)d_in[2];
    const float* b  = (const float*)d_in[3];

    int n = in_sizes[0] / D;        // 100000
    int e = in_sizes[1] / 2;        // 1600000
    int L = in_sizes[2] / (D * D);  // 3

    const int* srcI = ei;       // edge_index[0] : message source
    const int* dstI = ei + e;   // edge_index[1] : aggregation target

    // workspace carve (H first: keeps 16B alignment for float4)
    float* H         = (float*)d_ws;                  // n*128 floats (51.2 MB)
    int*   degi      = (int*)(H + (size_t)n * D);     // n
    int*   rowptr    = degi + n;                      // n+1
    int*   cursor    = rowptr + n + 1;                // n
    float* dis       = (float*)(cursor + n);          // n
    int*   col       = (int*)(dis + n);               // e
    int*   blocksums = col + e;                       // <=128

    hipMemsetAsync(degi, 0, (size_t)n * sizeof(int), stream);

    int shard_blocks = NSHARD * 256;  // 2048 blocks, shard = blockIdx & 7
    k_hist<<<shard_blocks, 256, 0, stream>>>(dstI, degi, e, n);

    int nscan = (n + 1023) / 1024;  // 98 blocks
    k_scan_local<<<nscan, 256, 0, stream>>>(degi, rowptr, blocksums, dis, n);
    k_scan_bsum<<<1, 128, 0, stream>>>(blocksums, nscan);
    int nb2 = (n + 255) / 256;
    k_scan_add<<<nb2, 256, 0, stream>>>(rowptr, cursor, blocksums, n, e);
    k_fill<<<shard_blocks, 256, 0, stream>>>(srcI, dstI, cursor, col, e, n);

    float*       out = (float*)d_out;
    const float* xin = x0;
    size_t lds_bytes = (size_t)(D * D + 32 * D) * sizeof(float);  // 80 KB
    for (int l = 0; l < L; ++l) {
        k_gemm<<<512, 256, lds_bytes, stream>>>(xin, W + (size_t)l * D * D, dis, H, n);
        k_agg<<<(n + 7) / 8, 256, 0, stream>>>(H, rowptr, col, dis, b + (size_t)l * D, out, n);
        xin = out;
    }
}

// Round 6
// 673.779 us; speedup vs baseline: 1.2875x; 1.1726x over previous
//
#include <hip/hip_runtime.h>

#define D 128
#define NSHARD 8

__device__ __forceinline__ unsigned short f2bf(float f) {
    union { float f; unsigned u; } c; c.f = f;
    unsigned u = c.u;
    return (unsigned short)((u + 0x7fffu + ((u >> 16) & 1u)) >> 16);  // RN
}
__device__ __forceinline__ float bf2f(unsigned short s) {
    union { unsigned u; float f; } c; c.u = ((unsigned)s) << 16;
    return c.f;
}

// ---------------------------------------------------------------------------
// CSR build: XCD-sharded histogram -> scan -> XCD-sharded fill.
// Shard s = blockIdx & 7 handles only dst in [s*per, (s+1)*per): under the
// default blockIdx%8 -> XCD mapping, all writes to one col/degi line come
// from a single XCD, so L2 assembles full lines (perf-only assumption).
// ---------------------------------------------------------------------------

__global__ __launch_bounds__(256) void k_hist(const int* __restrict__ dst,
                                              int* __restrict__ degi, int e, int n) {
    int s   = blockIdx.x & (NSHARD - 1);
    int per = (n + NSHARD - 1) / NSHARD;
    int lo  = s * per;
    int hi  = min(n, lo + per);
    const int4* d4 = (const int4*)dst;
    int e4     = e >> 2;
    int idx    = (blockIdx.x >> 3) * 256 + threadIdx.x;
    int stride = (gridDim.x >> 3) * 256;
    for (int i = idx; i < e4; i += stride) {
        int4 d = d4[i];
        if (d.x >= lo && d.x < hi) atomicAdd(&degi[d.x], 1);
        if (d.y >= lo && d.y < hi) atomicAdd(&degi[d.y], 1);
        if (d.z >= lo && d.z < hi) atomicAdd(&degi[d.z], 1);
        if (d.w >= lo && d.w < hi) atomicAdd(&degi[d.w], 1);
    }
    if (idx == 0) {  // scalar tail (e % 4), once per shard
        for (int i = e4 * 4; i < e; ++i) {
            int d = dst[i];
            if (d >= lo && d < hi) atomicAdd(&degi[d], 1);
        }
    }
}

// Per-block exclusive scan of 1024 elements (256 thr x 4), also computes
// dis[v] = rsqrt(deg_real + 1)  (the +1 is the self-loop).
__global__ __launch_bounds__(256) void k_scan_local(const int* __restrict__ degi,
                                                    int* __restrict__ rowptr,
                                                    int* __restrict__ blocksums,
                                                    float* __restrict__ dis, int n) {
    __shared__ int sd[256];
    int tid  = threadIdx.x;
    int base = blockIdx.x * 1024 + tid * 4;
    int v0 = 0, v1 = 0, v2 = 0, v3 = 0;
    if (base + 0 < n) v0 = degi[base + 0];
    if (base + 1 < n) v1 = degi[base + 1];
    if (base + 2 < n) v2 = degi[base + 2];
    if (base + 3 < n) v3 = degi[base + 3];
    if (base + 0 < n) dis[base + 0] = rsqrtf((float)(v0 + 1));
    if (base + 1 < n) dis[base + 1] = rsqrtf((float)(v1 + 1));
    if (base + 2 < n) dis[base + 2] = rsqrtf((float)(v2 + 1));
    if (base + 3 < n) dis[base + 3] = rsqrtf((float)(v3 + 1));
    int tsum = v0 + v1 + v2 + v3;
    sd[tid] = tsum;
    __syncthreads();
    for (int off = 1; off < 256; off <<= 1) {
        int add = (tid >= off) ? sd[tid - off] : 0;
        __syncthreads();
        sd[tid] += add;
        __syncthreads();
    }
    int incl = sd[tid];
    int excl = incl - tsum;
    if (tid == 255) blocksums[blockIdx.x] = incl;
    if (base + 0 < n) rowptr[base + 0] = excl;
    if (base + 1 < n) rowptr[base + 1] = excl + v0;
    if (base + 2 < n) rowptr[base + 2] = excl + v0 + v1;
    if (base + 3 < n) rowptr[base + 3] = excl + v0 + v1 + v2;
}

__global__ __launch_bounds__(128) void k_scan_bsum(int* __restrict__ bs, int nb) {
    __shared__ int sd[128];
    int t = threadIdx.x;
    int v = (t < nb) ? bs[t] : 0;
    sd[t] = v;
    __syncthreads();
    for (int off = 1; off < 128; off <<= 1) {
        int add = (t >= off) ? sd[t - off] : 0;
        __syncthreads();
        sd[t] += add;
        __syncthreads();
    }
    if (t < nb) bs[t] = sd[t] - v;  // exclusive
}

__global__ __launch_bounds__(256) void k_scan_add(int* __restrict__ rowptr,
                                                  int* __restrict__ cursor,
                                                  const int* __restrict__ blocksums,
                                                  int n, int total) {
    int i = blockIdx.x * 256 + threadIdx.x;
    if (i < n) {
        int r = rowptr[i] + blocksums[i >> 10];
        rowptr[i] = r;
        cursor[i] = r;
    }
    if (i == 0) rowptr[n] = total;
}

__global__ __launch_bounds__(256) void k_fill(const int* __restrict__ src,
                                              const int* __restrict__ dst,
                                              int* __restrict__ cursor,
                                              int* __restrict__ col, int e, int n) {
    int s   = blockIdx.x & (NSHARD - 1);
    int per = (n + NSHARD - 1) / NSHARD;
    int lo  = s * per;
    int hi  = min(n, lo + per);
    const int4* d4 = (const int4*)dst;
    const int4* s4 = (const int4*)src;
    int e4     = e >> 2;
    int idx    = (blockIdx.x >> 3) * 256 + threadIdx.x;
    int stride = (gridDim.x >> 3) * 256;
    for (int i = idx; i < e4; i += stride) {
        int4 d = d4[i];
        bool any = (d.x >= lo && d.x < hi) || (d.y >= lo && d.y < hi) ||
                   (d.z >= lo && d.z < hi) || (d.w >= lo && d.w < hi);
        if (!any) continue;
        int4 sc = s4[i];
        if (d.x >= lo && d.x < hi) col[atomicAdd(&cursor[d.x], 1)] = sc.x;
        if (d.y >= lo && d.y < hi) col[atomicAdd(&cursor[d.y], 1)] = sc.y;
        if (d.z >= lo && d.z < hi) col[atomicAdd(&cursor[d.z], 1)] = sc.z;
        if (d.w >= lo && d.w < hi) col[atomicAdd(&cursor[d.w], 1)] = sc.w;
    }
    if (idx == 0) {  // scalar tail, once per shard
        for (int i = e4 * 4; i < e; ++i) {
            int d = dst[i];
            if (d >= lo && d < hi) col[atomicAdd(&cursor[d], 1)] = src[i];
        }
    }
}

// ---------------------------------------------------------------------------
// h_bf16 = bf16( dis[v] * (x @ W[l]) ).
// W (64KB fp32) + 32-row x tile (16KB) in LDS -> 80KB, 2 blocks/CU.
// Register-prefetch double buffer: next tile's global loads are issued right
// after the staging barrier and consumed next iteration (latency hidden under
// the ~4096-cycle compute). Wave computes 8 rows; thread cols {l, l+64}
// (two b32 W reads: conflict-free; the float2 variant is a 4-way conflict).
// ---------------------------------------------------------------------------
__global__ __launch_bounds__(256) void k_gemm(const float* __restrict__ x,
                                              const float* __restrict__ W,
                                              const float* __restrict__ dis,
                                              unsigned short* __restrict__ h, int n) {
    extern __shared__ float smem[];
    float*  Ws  = smem;                     // 128*128 fp32
    float4* xs4 = (float4*)(smem + D * D);  // 32 rows * 32 float4
    {
        const float4* W4  = (const float4*)W;
        float4*       Ws4 = (float4*)Ws;
#pragma unroll
        for (int i = 0; i < 16; ++i)
            Ws4[threadIdx.x + i * 256] = W4[threadIdx.x + i * 256];
    }
    int wave = threadIdx.x >> 6;
    int lane = threadIdx.x & 63;
    const float4* X4 = (const float4*)x;
    size_t n4     = (size_t)n * (D / 4);
    int    ntiles = (n + 31) / 32;

    int    tile = blockIdx.x;
    float4 pf[4];
    {   // prefetch tile 0
        size_t base4 = (size_t)tile * 32 * (D / 4);
#pragma unroll
        for (int j = 0; j < 4; ++j) {
            size_t gi = base4 + threadIdx.x + j * 256;
            pf[j] = (tile < ntiles && gi < n4) ? X4[gi] : float4{0.f, 0.f, 0.f, 0.f};
        }
    }
    __syncthreads();  // W staged

    for (; tile < ntiles; tile += gridDim.x) {
#pragma unroll
        for (int j = 0; j < 4; ++j) xs4[threadIdx.x + j * 256] = pf[j];
        __syncthreads();

        int nt = tile + gridDim.x;  // issue next tile's loads (in flight all compute)
        if (nt < ntiles) {
            size_t base4 = (size_t)nt * 32 * (D / 4);
#pragma unroll
            for (int j = 0; j < 4; ++j) {
                size_t gi = base4 + threadIdx.x + j * 256;
                if (gi < n4) pf[j] = X4[gi];
            }
        }

        int   r0 = wave * 8;
        float al[8], ah[8];
#pragma unroll
        for (int r = 0; r < 8; ++r) { al[r] = 0.f; ah[r] = 0.f; }

#pragma unroll 4
        for (int k4 = 0; k4 < 32; ++k4) {
            float4 xr[8];
#pragma unroll
            for (int r = 0; r < 8; ++r) xr[r] = xs4[(r0 + r) * 32 + k4];
#pragma unroll
            for (int i = 0; i < 4; ++i) {
                float wl = Ws[(4 * k4 + i) * D + lane];
                float wh = Ws[(4 * k4 + i) * D + lane + 64];
#pragma unroll
                for (int r = 0; r < 8; ++r) {
                    float e = (&xr[r].x)[i];
                    al[r] = fmaf(e, wl, al[r]);
                    ah[r] = fmaf(e, wh, ah[r]);
                }
            }
        }

        int rowbase = tile * 32 + r0;
#pragma unroll
        for (int r = 0; r < 8; ++r) {
            int row = rowbase + r;
            if (row < n) {
                float dv = dis[row];
                unsigned short* hp = h + (size_t)row * D;
                hp[lane]      = f2bf(al[r] * dv);
                hp[lane + 64] = f2bf(ah[r] * dv);
            }
        }
        __syncthreads();  // xs free for next iteration's store
    }
}

// ---------------------------------------------------------------------------
// out[v] = relu( dis[v] * (hs[v] + sum_{s in N(v)} hs[s]) + b )
// h is bf16: row = 256B = 32 lanes x ushort4. Half-wave per node, 2 nodes per
// wave, 8-deep unrolled gather (2KB in flight per half-wave). fp32 accum.
// ---------------------------------------------------------------------------
__global__ __launch_bounds__(256) void k_agg(const unsigned short* __restrict__ h,
                                             const int* __restrict__ rowptr,
                                             const int* __restrict__ col,
                                             const float* __restrict__ dis,
                                             const float* __restrict__ b,
                                             float* __restrict__ out, int n) {
    int wave = threadIdx.x >> 6;
    int lane = threadIdx.x & 63;
    int half = lane >> 5;
    int hl   = lane & 31;
    int v = blockIdx.x * 8 + wave * 2 + half;
    if (v >= n) return;
    const ushort4* h4 = (const ushort4*)h;  // row = 32 ushort4

    ushort4 sv = h4[(size_t)v * 32 + hl];
    float ax[4] = {bf2f(sv.x), 0.f, 0.f, 0.f};
    float ay[4] = {bf2f(sv.y), 0.f, 0.f, 0.f};
    float az[4] = {bf2f(sv.z), 0.f, 0.f, 0.f};
    float aw[4] = {bf2f(sv.w), 0.f, 0.f, 0.f};

    int beg = rowptr[v], end = rowptr[v + 1];
    int i = beg;
    for (; i + 8 <= end; i += 8) {
        int c[8];
#pragma unroll
        for (int j = 0; j < 8; ++j) c[j] = col[i + j];
        ushort4 m[8];
#pragma unroll
        for (int j = 0; j < 8; ++j) m[j] = h4[(size_t)c[j] * 32 + hl];
#pragma unroll
        for (int j = 0; j < 8; ++j) {
            int q = j & 3;
            ax[q] += bf2f(m[j].x);
            ay[q] += bf2f(m[j].y);
            az[q] += bf2f(m[j].z);
            aw[q] += bf2f(m[j].w);
        }
    }
    for (; i < end; ++i) {
        ushort4 m = h4[(size_t)col[i] * 32 + hl];
        ax[0] += bf2f(m.x); ay[0] += bf2f(m.y);
        az[0] += bf2f(m.z); aw[0] += bf2f(m.w);
    }

    float  dv = dis[v];
    float4 bb = ((const float4*)b)[hl];
    float4 r;
    r.x = fmaxf(0.f, (ax[0] + ax[1] + ax[2] + ax[3]) * dv + bb.x);
    r.y = fmaxf(0.f, (ay[0] + ay[1] + ay[2] + ay[3]) * dv + bb.y);
    r.z = fmaxf(0.f, (az[0] + az[1] + az[2] + az[3]) * dv + bb.z);
    r.w = fmaxf(0.f, (aw[0] + aw[1] + aw[2] + aw[3]) * dv + bb.w);
    ((float4*)out)[(size_t)v * 32 + hl] = r;
}

// ---------------------------------------------------------------------------

extern "C" void kernel_launch(void* const* d_in, const int* in_sizes, int n_in,
                              void* d_out, int out_size, void* d_ws, size_t ws_size,
                              hipStream_t stream) {
    const float* x0 = (const float*)d_in[0];
    const int*   ei = (const int*)d_in[1];
    const float* W  = (const float*)d_in[2];
    const float* b  = (const float*)d_in[3];

    int n = in_sizes[0] / D;        // 100000
    int e = in_sizes[1] / 2;        // 1600000
    int L = in_sizes[2] / (D * D);  // 3

    const int* srcI = ei;       // edge_index[0] : message source
    const int* dstI = ei + e;   // edge_index[1] : aggregation target

    // workspace carve (H first: 25.6MB of bf16, byte offset stays 16B-aligned)
    unsigned short* H = (unsigned short*)d_ws;            // n*128 bf16
    int*   degi      = (int*)(H + (size_t)n * D);         // n
    int*   rowptr    = degi + n;                          // n+1
    int*   cursor    = rowptr + n + 1;                    // n
    float* dis       = (float*)(cursor + n);              // n
    int*   col       = (int*)(dis + n);                   // e
    int*   blocksums = col + e;                           // <=128

    hipMemsetAsync(degi, 0, (size_t)n * sizeof(int), stream);

    int shard_blocks = NSHARD * 256;  // 2048 blocks, shard = blockIdx & 7
    k_hist<<<shard_blocks, 256, 0, stream>>>(dstI, degi, e, n);

    int nscan = (n + 1023) / 1024;  // 98 blocks
    k_scan_local<<<nscan, 256, 0, stream>>>(degi, rowptr, blocksums, dis, n);
    k_scan_bsum<<<1, 128, 0, stream>>>(blocksums, nscan);
    int nb2 = (n + 255) / 256;
    k_scan_add<<<nb2, 256, 0, stream>>>(rowptr, cursor, blocksums, n, e);
    k_fill<<<shard_blocks, 256, 0, stream>>>(srcI, dstI, cursor, col, e, n);

    float*       out = (float*)d_out;
    const float* xin = x0;
    size_t lds_bytes = (size_t)(D * D + 32 * D) * sizeof(float);  // 80 KB
    for (int l = 0; l < L; ++l) {
        k_gemm<<<512, 256, lds_bytes, stream>>>(xin, W + (size_t)l * D * D, dis, H, n);
        k_agg<<<(n + 7) / 8, 256, 0, stream>>>(H, rowptr, col, dis, b + (size_t)l * D, out, n);
        xin = out;
    }
}

// Round 7
// 619.605 us; speedup vs baseline: 1.4001x; 1.0874x over previous
//
#include <hip/hip_runtime.h>

#define D 128
#define NSHARD 8

__device__ __forceinline__ unsigned short f2bf(float f) {
    union { float f; unsigned u; } c; c.f = f;
    unsigned u = c.u;
    return (unsigned short)((u + 0x7fffu + ((u >> 16) & 1u)) >> 16);  // RN
}
__device__ __forceinline__ float bf2f(unsigned short s) {
    union { unsigned u; float f; } c; c.u = ((unsigned)s) << 16;
    return c.f;
}

// ---------------------------------------------------------------------------
// CSR build: XCD-sharded histogram -> scan -> XCD-sharded fill.
// ---------------------------------------------------------------------------

__global__ __launch_bounds__(256) void k_hist(const int* __restrict__ dst,
                                              int* __restrict__ degi, int e, int n) {
    int s   = blockIdx.x & (NSHARD - 1);
    int per = (n + NSHARD - 1) / NSHARD;
    int lo  = s * per;
    int hi  = min(n, lo + per);
    const int4* d4 = (const int4*)dst;
    int e4     = e >> 2;
    int idx    = (blockIdx.x >> 3) * 256 + threadIdx.x;
    int stride = (gridDim.x >> 3) * 256;
    for (int i = idx; i < e4; i += stride) {
        int4 d = d4[i];
        if (d.x >= lo && d.x < hi) atomicAdd(&degi[d.x], 1);
        if (d.y >= lo && d.y < hi) atomicAdd(&degi[d.y], 1);
        if (d.z >= lo && d.z < hi) atomicAdd(&degi[d.z], 1);
        if (d.w >= lo && d.w < hi) atomicAdd(&degi[d.w], 1);
    }
    if (idx == 0) {  // scalar tail (e % 4), once per shard
        for (int i = e4 * 4; i < e; ++i) {
            int d = dst[i];
            if (d >= lo && d < hi) atomicAdd(&degi[d], 1);
        }
    }
}

// Per-block exclusive scan of 1024 elements (256 thr x 4), also computes
// dis[v] = rsqrt(deg_real + 1)  (the +1 is the self-loop).
__global__ __launch_bounds__(256) void k_scan_local(const int* __restrict__ degi,
                                                    int* __restrict__ rowptr,
                                                    int* __restrict__ blocksums,
                                                    float* __restrict__ dis, int n) {
    __shared__ int sd[256];
    int tid  = threadIdx.x;
    int base = blockIdx.x * 1024 + tid * 4;
    int v0 = 0, v1 = 0, v2 = 0, v3 = 0;
    if (base + 0 < n) v0 = degi[base + 0];
    if (base + 1 < n) v1 = degi[base + 1];
    if (base + 2 < n) v2 = degi[base + 2];
    if (base + 3 < n) v3 = degi[base + 3];
    if (base + 0 < n) dis[base + 0] = rsqrtf((float)(v0 + 1));
    if (base + 1 < n) dis[base + 1] = rsqrtf((float)(v1 + 1));
    if (base + 2 < n) dis[base + 2] = rsqrtf((float)(v2 + 1));
    if (base + 3 < n) dis[base + 3] = rsqrtf((float)(v3 + 1));
    int tsum = v0 + v1 + v2 + v3;
    sd[tid] = tsum;
    __syncthreads();
    for (int off = 1; off < 256; off <<= 1) {
        int add = (tid >= off) ? sd[tid - off] : 0;
        __syncthreads();
        sd[tid] += add;
        __syncthreads();
    }
    int incl = sd[tid];
    int excl = incl - tsum;
    if (tid == 255) blocksums[blockIdx.x] = incl;
    if (base + 0 < n) rowptr[base + 0] = excl;
    if (base + 1 < n) rowptr[base + 1] = excl + v0;
    if (base + 2 < n) rowptr[base + 2] = excl + v0 + v1;
    if (base + 3 < n) rowptr[base + 3] = excl + v0 + v1 + v2;
}

__global__ __launch_bounds__(128) void k_scan_bsum(int* __restrict__ bs, int nb) {
    __shared__ int sd[128];
    int t = threadIdx.x;
    int v = (t < nb) ? bs[t] : 0;
    sd[t] = v;
    __syncthreads();
    for (int off = 1; off < 128; off <<= 1) {
        int add = (t >= off) ? sd[t - off] : 0;
        __syncthreads();
        sd[t] += add;
        __syncthreads();
    }
    if (t < nb) bs[t] = sd[t] - v;  // exclusive
}

__global__ __launch_bounds__(256) void k_scan_add(int* __restrict__ rowptr,
                                                  int* __restrict__ cursor,
                                                  const int* __restrict__ blocksums,
                                                  int n, int total) {
    int i = blockIdx.x * 256 + threadIdx.x;
    if (i < n) {
        int r = rowptr[i] + blocksums[i >> 10];
        rowptr[i] = r;
        cursor[i] = r;
    }
    if (i == 0) rowptr[n] = total;
}

__global__ __launch_bounds__(256) void k_fill(const int* __restrict__ src,
                                              const int* __restrict__ dst,
                                              int* __restrict__ cursor,
                                              int* __restrict__ col, int e, int n) {
    int s   = blockIdx.x & (NSHARD - 1);
    int per = (n + NSHARD - 1) / NSHARD;
    int lo  = s * per;
    int hi  = min(n, lo + per);
    const int4* d4 = (const int4*)dst;
    const int4* s4 = (const int4*)src;
    int e4     = e >> 2;
    int idx    = (blockIdx.x >> 3) * 256 + threadIdx.x;
    int stride = (gridDim.x >> 3) * 256;
    for (int i = idx; i < e4; i += stride) {
        int4 d = d4[i];
        bool any = (d.x >= lo && d.x < hi) || (d.y >= lo && d.y < hi) ||
                   (d.z >= lo && d.z < hi) || (d.w >= lo && d.w < hi);
        if (!any) continue;
        int4 sc = s4[i];
        if (d.x >= lo && d.x < hi) col[atomicAdd(&cursor[d.x], 1)] = sc.x;
        if (d.y >= lo && d.y < hi) col[atomicAdd(&cursor[d.y], 1)] = sc.y;
        if (d.z >= lo && d.z < hi) col[atomicAdd(&cursor[d.z], 1)] = sc.z;
        if (d.w >= lo && d.w < hi) col[atomicAdd(&cursor[d.w], 1)] = sc.w;
    }
    if (idx == 0) {  // scalar tail, once per shard
        for (int i = e4 * 4; i < e; ++i) {
            int d = dst[i];
            if (d >= lo && d < hi) col[atomicAdd(&cursor[d], 1)] = src[i];
        }
    }
}

// ---------------------------------------------------------------------------
// h_bf16 = bf16( dis[v] * (x @ W[l]) ).
// W (64KB fp32) + 32-row x tile (16KB) in LDS -> 80KB, 2 blocks/CU.
// Thread computes 4 rows x 4 cols (float4 acc): per k4 the wave issues
// 4 x-reads + 4 W-reads (all ds_read_b128, 2-way broadcast = free) feeding
// 128 FMAs/thread -> ~96 LDS cyc vs 256 VALU cyc = VALU-bound (~75%).
// Wave w -> rows w*8+ (lane>>5)*4 .. +3; cols 4*(lane&31) .. +3.
// Register-prefetch double buffer hides HBM latency of the next x tile.
// ---------------------------------------------------------------------------
__global__ __launch_bounds__(256) void k_gemm(const float* __restrict__ x,
                                              const float* __restrict__ W,
                                              const float* __restrict__ dis,
                                              unsigned short* __restrict__ h, int n) {
    extern __shared__ float smem[];
    float4* Ws4 = (float4*)smem;            // [128 k][32 col-groups]
    float4* xs4 = (float4*)(smem + D * D);  // [32 rows][32 k-groups]
    {
        const float4* W4 = (const float4*)W;
#pragma unroll
        for (int i = 0; i < 16; ++i)
            Ws4[threadIdx.x + i * 256] = W4[threadIdx.x + i * 256];
    }
    int wave  = threadIdx.x >> 6;
    int lane  = threadIdx.x & 63;
    int rbase = wave * 8 + (lane >> 5) * 4;  // local row base (4 rows)
    int cg    = lane & 31;                   // col-group (4 cols)

    const float4* X4 = (const float4*)x;
    size_t n4     = (size_t)n * (D / 4);
    int    ntiles = (n + 31) / 32;

    int    tile = blockIdx.x;
    float4 pf[4];
    {   // prefetch tile 0
        size_t base4 = (size_t)tile * 32 * (D / 4);
#pragma unroll
        for (int j = 0; j < 4; ++j) {
            size_t gi = base4 + threadIdx.x + j * 256;
            pf[j] = (tile < ntiles && gi < n4) ? X4[gi] : float4{0.f, 0.f, 0.f, 0.f};
        }
    }
    __syncthreads();  // W staged

    for (; tile < ntiles; tile += gridDim.x) {
#pragma unroll
        for (int j = 0; j < 4; ++j) xs4[threadIdx.x + j * 256] = pf[j];
        __syncthreads();

        int nt = tile + gridDim.x;  // issue next tile's loads (in flight all compute)
        if (nt < ntiles) {
            size_t base4 = (size_t)nt * 32 * (D / 4);
#pragma unroll
            for (int j = 0; j < 4; ++j) {
                size_t gi = base4 + threadIdx.x + j * 256;
                if (gi < n4) pf[j] = X4[gi];
            }
        }

        float4 acc[4];
#pragma unroll
        for (int r = 0; r < 4; ++r) acc[r] = float4{0.f, 0.f, 0.f, 0.f};

#pragma unroll 4
        for (int k4 = 0; k4 < 32; ++k4) {
            float4 xr[4];
#pragma unroll
            for (int r = 0; r < 4; ++r) xr[r] = xs4[(rbase + r) * 32 + k4];
            float4 wv[4];
#pragma unroll
            for (int i = 0; i < 4; ++i) wv[i] = Ws4[(4 * k4 + i) * 32 + cg];
#pragma unroll
            for (int i = 0; i < 4; ++i) {
#pragma unroll
                for (int r = 0; r < 4; ++r) {
                    float e = (&xr[r].x)[i];
                    acc[r].x = fmaf(e, wv[i].x, acc[r].x);
                    acc[r].y = fmaf(e, wv[i].y, acc[r].y);
                    acc[r].z = fmaf(e, wv[i].z, acc[r].z);
                    acc[r].w = fmaf(e, wv[i].w, acc[r].w);
                }
            }
        }

        int grow = tile * 32 + rbase;
        ushort4* h4 = (ushort4*)h;  // row = 32 ushort4 (4 bf16 each)
#pragma unroll
        for (int r = 0; r < 4; ++r) {
            int row = grow + r;
            if (row < n) {
                float dv = dis[row];
                ushort4 o;
                o.x = f2bf(acc[r].x * dv);
                o.y = f2bf(acc[r].y * dv);
                o.z = f2bf(acc[r].z * dv);
                o.w = f2bf(acc[r].w * dv);
                h4[(size_t)row * 32 + cg] = o;
            }
        }
        __syncthreads();  // xs free for next iteration's store
    }
}

// ---------------------------------------------------------------------------
// out[v] = relu( dis[v] * (hs[v] + sum_{s in N(v)} hs[s]) + b )
// h is bf16: row = 256B = 32 lanes x ushort4. Half-wave per node, 2 nodes per
// wave, 8-deep unrolled gather (2KB in flight per half-wave). fp32 accum.
// ---------------------------------------------------------------------------
__global__ __launch_bounds__(256) void k_agg(const unsigned short* __restrict__ h,
                                             const int* __restrict__ rowptr,
                                             const int* __restrict__ col,
                                             const float* __restrict__ dis,
                                             const float* __restrict__ b,
                                             float* __restrict__ out, int n) {
    int wave = threadIdx.x >> 6;
    int lane = threadIdx.x & 63;
    int half = lane >> 5;
    int hl   = lane & 31;
    int v = blockIdx.x * 8 + wave * 2 + half;
    if (v >= n) return;
    const ushort4* h4 = (const ushort4*)h;  // row = 32 ushort4

    ushort4 sv = h4[(size_t)v * 32 + hl];
    float ax[4] = {bf2f(sv.x), 0.f, 0.f, 0.f};
    float ay[4] = {bf2f(sv.y), 0.f, 0.f, 0.f};
    float az[4] = {bf2f(sv.z), 0.f, 0.f, 0.f};
    float aw[4] = {bf2f(sv.w), 0.f, 0.f, 0.f};

    int beg = rowptr[v], end = rowptr[v + 1];
    int i = beg;
    for (; i + 8 <= end; i += 8) {
        int c[8];
#pragma unroll
        for (int j = 0; j < 8; ++j) c[j] = col[i + j];
        ushort4 m[8];
#pragma unroll
        for (int j = 0; j < 8; ++j) m[j] = h4[(size_t)c[j] * 32 + hl];
#pragma unroll
        for (int j = 0; j < 8; ++j) {
            int q = j & 3;
            ax[q] += bf2f(m[j].x);
            ay[q] += bf2f(m[j].y);
            az[q] += bf2f(m[j].z);
            aw[q] += bf2f(m[j].w);
        }
    }
    for (; i < end; ++i) {
        ushort4 m = h4[(size_t)col[i] * 32 + hl];
        ax[0] += bf2f(m.x); ay[0] += bf2f(m.y);
        az[0] += bf2f(m.z); aw[0] += bf2f(m.w);
    }

    float  dv = dis[v];
    float4 bb = ((const float4*)b)[hl];
    float4 r;
    r.x = fmaxf(0.f, (ax[0] + ax[1] + ax[2] + ax[3]) * dv + bb.x);
    r.y = fmaxf(0.f, (ay[0] + ay[1] + ay[2] + ay[3]) * dv + bb.y);
    r.z = fmaxf(0.f, (az[0] + az[1] + az[2] + az[3]) * dv + bb.z);
    r.w = fmaxf(0.f, (aw[0] + aw[1] + aw[2] + aw[3]) * dv + bb.w);
    ((float4*)out)[(size_t)v * 32 + hl] = r;
}

// ---------------------------------------------------------------------------

extern "C" void kernel_launch(void* const* d_in, const int* in_sizes, int n_in,
                              void* d_out, int out_size, void* d_ws, size_t ws_size,
                              hipStream_t stream) {
    const float* x0 = (const float*)d_in[0];
    const int*   ei = (const int*)d_in[1];
    const float* W  = (const float*)d_in[2];
    const float* b  = (const float*)d_in[3];

    int n = in_sizes[0] / D;        // 100000
    int e = in_sizes[1] / 2;        // 1600000
    int L = in_sizes[2] / (D * D);  // 3

    const int* srcI = ei;       // edge_index[0] : message source
    const int* dstI = ei + e;   // edge_index[1] : aggregation target

    // workspace carve (H first: 25.6MB of bf16, byte offset stays 16B-aligned)
    unsigned short* H = (unsigned short*)d_ws;            // n*128 bf16
    int*   degi      = (int*)(H + (size_t)n * D);         // n
    int*   rowptr    = degi + n;                          // n+1
    int*   cursor    = rowptr + n + 1;                    // n
    float* dis       = (float*)(cursor + n);              // n
    int*   col       = (int*)(dis + n);                   // e
    int*   blocksums = col + e;                           // <=128

    hipMemsetAsync(degi, 0, (size_t)n * sizeof(int), stream);

    int shard_blocks = NSHARD * 256;  // 2048 blocks, shard = blockIdx & 7
    k_hist<<<shard_blocks, 256, 0, stream>>>(dstI, degi, e, n);

    int nscan = (n + 1023) / 1024;  // 98 blocks
    k_scan_local<<<nscan, 256, 0, stream>>>(degi, rowptr, blocksums, dis, n);
    k_scan_bsum<<<1, 128, 0, stream>>>(blocksums, nscan);
    int nb2 = (n + 255) / 256;
    k_scan_add<<<nb2, 256, 0, stream>>>(rowptr, cursor, blocksums, n, e);
    k_fill<<<shard_blocks, 256, 0, stream>>>(srcI, dstI, cursor, col, e, n);

    float*       out = (float*)d_out;
    const float* xin = x0;
    size_t lds_bytes = (size_t)(D * D + 32 * D) * sizeof(float);  // 80 KB
    for (int l = 0; l < L; ++l) {
        k_gemm<<<512, 256, lds_bytes, stream>>>(xin, W + (size_t)l * D * D, dis, H, n);
        k_agg<<<(n + 7) / 8, 256, 0, stream>>>(H, rowptr, col, dis, b + (size_t)l * D, out, n);
        xin = out;
    }
}